// Round 17
// baseline (660.914 us; speedup 1.0000x reference)
//
#include <hip/hip_runtime.h>
#include <hip/hip_fp16.h>

// Weight-stationary LSTM classifier — L2-RESIDENT exchange ring (round 16b,
// compile fix: nontemporal loads use native ext_vector float4, not
// HIP_vector_type). R15 post-mortem: WRITE_SIZE 111MB == entire exchange
// hitting HBM. The deep "virgin slot" rotation (depth<=23) had a 15MB/XCD
// footprint >> 4MB L2 -> every exchange line evicted before reuse; all reads
// LLC/HBM-latency. Fix: depth FORCED to 3 (minimum for 2-ahead x staging;
// 2MB/XCD < L2). Slots rewritten in place -> dirty lines stay in XCD L2.
// Acquire fence (L1 inv, dirty-L2 preserved) on slot reuse = cheap.
// Embed gather via nontemporal loads (stream-once; don't evict hot ring).
// Rest verbatim R15/R12: 248 wgs self-registered to physical XCD via XCC_ID
// (group==XCD by construction -> all flag stores relaxed, never wbl2);
// 8 groups x 512 rows x 19 wgs (16 jh x 4 gates), 1024 thr; W frag-blocked
// in LDS (conflict-free); exchange slots in MFMA frag layout; xpart before
// wait; scalar h-store (R12 form). d_ws: [0,64KB) flags+cnt, 3 slots.

#define TT 22
#define STEPS 22
#define NB 19
#define NWG 248
#define NTHR 1024
#define KTOT 20                  // kt blocks (640 halves: x 0..319 | h 320..639)
#define BUFELT ((size_t)256 * KTOT * 512)
#define SROWS 27                 // staging rows per wg (ceil 512/19)

typedef _Float16 f16;
typedef _Float16 f16x8 __attribute__((ext_vector_type(8)));
typedef float    f32x4 __attribute__((ext_vector_type(4)));
typedef float    fv4   __attribute__((ext_vector_type(4)));   // native vec for NT loads

__device__ __forceinline__ float sigm(float x) { return 1.0f / (1.0f + __expf(-x)); }
__device__ __forceinline__ float tanh_f(float x) {
    float ax = fabsf(x);
    float e = __expf(-2.0f * ax);
    return copysignf((1.0f - e) / (1.0f + e), x);
}
__device__ __forceinline__ f16x8 pack8v(fv4 a, fv4 b) {
    f16x8 v;
    v[0] = (f16)a.x; v[1] = (f16)a.y; v[2] = (f16)a.z; v[3] = (f16)a.w;
    v[4] = (f16)b.x; v[5] = (f16)b.y; v[6] = (f16)b.z; v[7] = (f16)b.w;
    return v;
}

__global__ __launch_bounds__(NTHR, 4)
void lstm_ws(const int* __restrict__ cap, const int* __restrict__ cap_len,
             const float* __restrict__ embed,
             const float* __restrict__ Wih, const float* __restrict__ Whh,
             const float* __restrict__ bih, const float* __restrict__ bhh,
             const float* __restrict__ v_wn, const float* __restrict__ g_wn,
             const float* __restrict__ b_cls,
             f16* __restrict__ bufs, int depth,
             unsigned* __restrict__ bar, float* __restrict__ out)
{
    __shared__ f16 Wl[84 * 512];        // 84 KB (80KB W + pad) -> 1 wg/CU
    __shared__ int capS[SROWS][TT];
    __shared__ float scaleS[2];
    __shared__ int roleS;

    const int tid = threadIdx.x;
    const int wv = tid >> 6, ln = tid & 63, c = ln & 15, kg = ln >> 4;

    // entry hygiene: drop stale L1/clean-L2 lines from a previous replay
    __builtin_amdgcn_fence(__ATOMIC_ACQUIRE, "agent");

    // ---- self-registration: role = (physical XCD, slot) ----
    unsigned* cnt = bar + 12288;        // 8 counters, 256B apart
    if (tid == 0) {
        unsigned xcc;
        asm volatile("s_getreg_b32 %0, hwreg(HW_REG_XCC_ID)" : "=s"(xcc));
        unsigned s = __hip_atomic_fetch_add(cnt + xcc * 64, 1u,
                                            __ATOMIC_RELAXED,
                                            __HIP_MEMORY_SCOPE_AGENT);
        roleS = (int)(xcc * 32 + s);
    }
    __syncthreads();
    const int grp = roleS >> 5;
    const int nb  = roleS & 31;
    if (nb >= NB) return;               // surplus wg: exit (group has its 19)

    const int mrow0 = grp * 512;
    unsigned* flags = bar + grp * 1024; // wg flag at + nb*32

    auto slot = [&](int n) { return bufs + (size_t)(n % depth) * BUFELT; };

    // ---- W -> LDS, fragment-blocked (conflict-free b128 reads) ----
    for (int u = tid; u < 80 * 64; u += NTHR) {
        int f = u >> 6, l = u & 63;
        int g = f / KTOT, kt = f - g * KTOT;
        int cc = l & 15, kgg = l >> 4;
        int jh0 = nb * 16 + cc;
        int j = g * 300 + jh0;
        int kb = kt * 32 + kgg * 8;
        f16x8 v;
        #pragma unroll
        for (int i = 0; i < 8; ++i) {
            int kk = kb + i;
            float x = 0.f;
            if (jh0 < 300) {
                if (kk < 300)                   x = Wih[(size_t)j * 300 + kk];
                else if (kk >= 320 && kk < 620) x = Whh[(size_t)j * 300 + (kk - 320)];
            }
            v[i] = (f16)x;
        }
        *(f16x8*)&Wl[(size_t)f * 512 + l * 8] = v;
    }

    const int srow0 = nb * SROWS;
    const int nr = (512 - srow0) < SROWS ? (512 - srow0) : SROWS;  // 27/26
    for (int u = tid; u < SROWS * TT; u += NTHR) {
        int rl = u / TT, t = u - rl * TT;
        if (rl < nr) capS[rl][t] = cap[(size_t)(mrow0 + srow0 + rl) * TT + t];
    }
    if (tid < 2) {
        float s = 0.f;
        for (int k = 0; k < 300; ++k) { float v = v_wn[tid * 300 + k]; s += v * v; }
        scaleS[tid] = g_wn[tid] * rsqrtf(s);
    }
    __syncthreads();

    // ---- x staging (nontemporal embed reads: stream-once, keep ring hot) ----
    auto stage_x = [&](int t, f16* bufn) {
        for (int u = tid; u < nr * 40; u += NTHR) {
            int rl = u / 40, k8 = u - rl * 40;
            int grow = mrow0 + srow0 + rl;
            const float* er = embed + (size_t)capS[rl][t] * 300;
            int k0 = k8 * 8;
            f16x8 v;
            if (k0 < 296) {
                fv4 a = __builtin_nontemporal_load((const fv4*)(er + k0));
                fv4 bb = __builtin_nontemporal_load((const fv4*)(er + k0 + 4));
                v = pack8v(a, bb);
            } else if (k0 == 296) {
                fv4 a = __builtin_nontemporal_load((const fv4*)(er + 296));
                v[0] = (f16)a.x; v[1] = (f16)a.y; v[2] = (f16)a.z; v[3] = (f16)a.w;
                v[4] = v[5] = v[6] = v[7] = (f16)0.f;
            } else {
                #pragma unroll
                for (int i = 0; i < 8; ++i) v[i] = (f16)0.f;
            }
            size_t off = ((size_t)((grow >> 4) * KTOT + (k8 >> 2))) * 512
                         + (grow & 15) * 32 + (k8 & 3) * 8;
            *(f16x8*)(bufn + off) = v;
        }
    };

    // ---- group barrier: arrive ALWAYS relaxed (same-XCD by construction) ----
    auto arrive = [&](unsigned ph) {
        __syncthreads();   // drains all waves' vmem stores (into shared L2)
        if (tid == 0)
            __hip_atomic_store(flags + nb * 32, ph, __ATOMIC_RELAXED,
                               __HIP_MEMORY_SCOPE_AGENT);
    };
    auto wait = [&](unsigned ph, bool fen) {
        if (tid < NB) {
            while (__hip_atomic_load(flags + tid * 32, __ATOMIC_RELAXED,
                                     __HIP_MEMORY_SCOPE_AGENT) < ph)
                __builtin_amdgcn_s_sleep(1);
        }
        if (fen)   // slot reuse: invalidate stale L1 (dirty L2 preserved)
            __builtin_amdgcn_fence(__ATOMIC_ACQUIRE, "agent");
        __syncthreads();
    };

    // per-lane constants
    size_t aoff[2];
    #pragma unroll
    for (int m = 0; m < 2; ++m)
        aoff[m] = (size_t)(((mrow0 >> 4) + wv * 2 + m) * KTOT) * 512
                  + c * 32 + kg * 8;
    int wbase[4];
    #pragma unroll
    for (int g = 0; g < 4; ++g) wbase[g] = g * KTOT * 512 + ln * 8;

    const int jh = nb * 16 + c;
    float bias[4];
    #pragma unroll
    for (int g = 0; g < 4; ++g) {
        float bv = 0.f;
        if (jh < 300) { int j = g * 300 + jh; bv = bih[j] + bhh[j]; }
        bias[g] = bv;
    }
    int lenr[2][4];
    #pragma unroll
    for (int m = 0; m < 2; ++m) {
        int rb = mrow0 + wv * 32 + m * 16 + kg * 4;
        #pragma unroll
        for (int rg = 0; rg < 4; ++rg) lenr[m][rg] = cap_len[rb + rg];
    }
    // h-store swizzle constants (col k = 320 + jh), R12 form
    const int hkt  = (320 + jh) >> 5;
    const int hkgd = ((320 + jh) >> 3) & 3;
    const int hel  = jh & 7;

    float cst[2][4] = {};
    float hreg[2][4] = {};
    f32x4 acc[2][4];

    auto xpart = [&](const f16* bufc) {
        #pragma unroll
        for (int kt = 0; kt < 10; ++kt) {
            f16x8 av[2];
            #pragma unroll
            for (int m = 0; m < 2; ++m)
                av[m] = *(const f16x8*)(bufc + aoff[m] + kt * 512);
            #pragma unroll
            for (int g = 0; g < 4; ++g) {
                f16x8 bv = *(const f16x8*)&Wl[wbase[g] + kt * 512];
                #pragma unroll
                for (int m = 0; m < 2; ++m)
                    acc[m][g] = __builtin_amdgcn_mfma_f32_16x16x32_f16(av[m], bv, acc[m][g], 0, 0, 0);
            }
        }
    };
    auto hpart = [&](const f16* bufc) {
        #pragma unroll
        for (int kt = 10; kt < KTOT; ++kt) {
            f16x8 av[2];
            #pragma unroll
            for (int m = 0; m < 2; ++m)
                av[m] = *(const f16x8*)(bufc + aoff[m] + kt * 512);
            #pragma unroll
            for (int g = 0; g < 4; ++g) {
                f16x8 bv = *(const f16x8*)&Wl[wbase[g] + kt * 512];
                #pragma unroll
                for (int m = 0; m < 2; ++m)
                    acc[m][g] = __builtin_amdgcn_mfma_f32_16x16x32_f16(av[m], bv, acc[m][g], 0, 0, 0);
            }
        }
    };

    const bool ahead2 = (depth >= 3);
    stage_x(0, slot(0));                 // slot0 fully memset (h_0=0 + pads)
    if (ahead2) stage_x(1, slot(1));
    arrive(1);
    wait(1, false);

    #pragma unroll 1
    for (int t = 0; t < STEPS; ++t) {
        const f16* bufc = slot(t);
        #pragma unroll
        for (int m = 0; m < 2; ++m)
            #pragma unroll
            for (int g = 0; g < 4; ++g) {
                float bv = bias[g];
                f32x4 b4 = {bv, bv, bv, bv};
                acc[m][g] = b4;
            }

        bool reuse = (unsigned)(t + 1) >= (unsigned)depth;
        if (ahead2) {
            xpart(bufc);                  // x(t) covered by wait(t) last iter
            wait((unsigned)(t + 1), reuse);
        } else {
            wait((unsigned)(t + 1), reuse);
            xpart(bufc);
        }
        hpart(bufc);

        // gates (i/f/g/o same-lane acc regs) + scalar swizzled h store
        f16* bufn = slot(t + 1);
        #pragma unroll
        for (int m = 0; m < 2; ++m) {
            int rtile = (mrow0 >> 4) + wv * 2 + m;
            size_t hb = ((size_t)(rtile * KTOT + hkt)) * 512 + hkgd * 8 + hel;
            #pragma unroll
            for (int rg = 0; rg < 4; ++rg) {
                bool upd = (t < lenr[m][rg]);
                float iv = sigm(acc[m][0][rg]);
                float fv = sigm(acc[m][1][rg]);
                float gv = tanh_f(acc[m][2][rg]);
                float ov = sigm(acc[m][3][rg]);
                float cn = fv * cst[m][rg] + iv * gv;
                cn = upd ? cn : cst[m][rg];
                cst[m][rg] = cn;
                float hn = ov * tanh_f(cn);
                hreg[m][rg] = upd ? hn : hreg[m][rg];
                f16 hv = (jh < 300) ? (f16)hreg[m][rg] : (f16)0.f;
                bufn[hb + (size_t)(kg * 4 + rg) * 32] = hv;
            }
        }

        if (ahead2) { if (t + 2 < STEPS) stage_x(t + 2, slot(t + 2)); }
        else        { if (t + 1 < STEPS) stage_x(t + 1, slot(t + 1)); }
        arrive((unsigned)(t + 2));
    }

    wait((unsigned)(STEPS + 1), true);

    // ---- head: this wg's staged rows, swizzled h reads ----
    const f16* hb = slot(STEPS);
    for (int u = tid; u < nr * 2; u += NTHR) {
        int rl = u >> 1, cls = u & 1;
        int grow = mrow0 + srow0 + rl;
        float sc = scaleS[cls];
        const float* vr = v_wn + cls * 300;
        size_t rbase = ((size_t)((grow >> 4) * KTOT)) * 512 + (grow & 15) * 32;
        float s = 0.f;
        #pragma unroll 4
        for (int k = 0; k < 300; ++k) {
            int k2 = 320 + k;
            size_t off = rbase + (size_t)(k2 >> 5) * 512 + ((k2 >> 3) & 3) * 8 + (k2 & 7);
            s += vr[k] * (float)hb[off];
        }
        out[(size_t)grow * 2 + cls] = sc * s + b_cls[cls];
    }
}

extern "C" void kernel_launch(void* const* d_in, const int* in_sizes, int n_in,
                              void* d_out, int out_size, void* d_ws, size_t ws_size,
                              hipStream_t stream) {
    const int*   cap     = (const int*)  d_in[0];
    const int*   cap_len = (const int*)  d_in[1];
    const float* embed   = (const float*)d_in[2];
    const float* W_ih    = (const float*)d_in[3];
    const float* W_hh    = (const float*)d_in[4];
    const float* b_ih    = (const float*)d_in[5];
    const float* b_hh    = (const float*)d_in[6];
    const float* v_wn    = (const float*)d_in[7];
    const float* g_wn    = (const float*)d_in[8];
    const float* b_cls   = (const float*)d_in[9];
    float* out = (float*)d_out;

    unsigned* bar = (unsigned*)d_ws;
    f16* bufs = (f16*)((char*)d_ws + 65536);
    size_t slot_bytes = BUFELT * sizeof(f16);          // 5,242,880
    int depth = (int)((ws_size > 65536 ? ws_size - 65536 : 0) / slot_bytes);
    if (depth > 3) depth = 3;   // L2-RESIDENT ring: 3 slots = 2MB/XCD < 4MB L2
    if (depth < 2) depth = 2;

    hipMemsetAsync(bar, 0, 65536, stream);             // flags + reg counters
    hipMemsetAsync(bufs, 0, slot_bytes, stream);       // slot 0 (h_0=0 + pads)

    lstm_ws<<<NWG, NTHR, 0, stream>>>(cap, cap_len, embed, W_ih, W_hh, b_ih, b_hh,
                                      v_wn, g_wn, b_cls, bufs, depth, bar, out);
}

// Round 19
// 519.040 us; speedup vs baseline: 1.2733x; 1.2733x over previous
//
#include <hip/hip_runtime.h>
#include <hip/hip_fp16.h>

// NO-SYNC LSTM classifier (round 18b: crash+layout fixes).
// R7-R17 lesson: any cross-wg h-exchange costs ~15-20us/step in sync/
// coherence on MI355X regardless of protocol. Eliminate it: 128 wgs x 32
// rows; each wg computes ALL gate columns for its rows; h stays in LDS
// (ping-pong A=[x 0..299 | h 300..599 | pad] in MFMA-fragment layout).
// W is pre-arranged fragment-blocked in d_ws by prep_w (1.52MB, shared L2
// image per XCD) and streamed global->VGPR each step. ONE intra-wg
// __syncthreads per step; no flags, no fences, no atomics.
// Fixes vs R18: (1) __syncthreads between capS/zero setup and stage_x(0)
// (missing barrier -> garbage tokens -> wild embed reads -> GPU fault);
// (2) A-fragment read offset c*32+kg*8 (row=lane&15, quad=lane>>4), not
// ln*8; (3) both A buffers zeroed (pad k600..607 never written; NaN x 0
// poisons MFMA otherwise).
// Wave n-tile split (19 live jh-tiles): wave w owns {w, w+8} (+{16+w} if
// w<3); x4 gates. LDS 84.7KB -> 1 wg/CU. d_ws: Wc only.

#define TT 22
#define STEPS 22
#define NROW 32
#define NWGD 128
#define NTHR 512                 // 8 waves, 2/SIMD
#define NKT 19                   // K = 608 (x 300 | h 300 | pad 8)
#define ASTRIDE 20480            // halves per A buffer (19456 used, padded)

typedef _Float16 f16;
typedef _Float16 f16x4 __attribute__((ext_vector_type(4)));
typedef _Float16 f16x8 __attribute__((ext_vector_type(8)));
typedef float    f32x4 __attribute__((ext_vector_type(4)));

__device__ __forceinline__ float sigm(float x) { return 1.0f / (1.0f + __expf(-x)); }
__device__ __forceinline__ float tanh_f(float x) {
    float ax = fabsf(x);
    float e = __expf(-2.0f * ax);
    return copysignf((1.0f - e) / (1.0f + e), x);
}

// Wc fragment f = (g*20 + tw)*19 + kt : 1KB block, lane l holds
// col = tw*16 + (l&15) of gate g, k = kt*32 + (l>>4)*8 .. +8.
__global__ void prep_w(const float* __restrict__ Wih, const float* __restrict__ Whh,
                       f16* __restrict__ Wc) {
    int f = blockIdx.x;             // 0..1519
    int n = f / NKT, kt = f - n * NKT;
    int g = n / 20, tw = n - g * 20;
    int l = threadIdx.x;            // 0..63
    int jh = tw * 16 + (l & 15);
    int kb = kt * 32 + (l >> 4) * 8;
    f16x8 v;
    #pragma unroll
    for (int i = 0; i < 8; ++i) {
        int k = kb + i;
        float x = 0.f;
        if (jh < 300) {
            if (k < 300)      x = Wih[(size_t)(g * 300 + jh) * 300 + k];
            else if (k < 600) x = Whh[(size_t)(g * 300 + jh) * 300 + (k - 300)];
        }
        v[i] = (f16)x;
    }
    *(f16x8*)&Wc[(size_t)f * 512 + l * 8] = v;
}

__global__ __launch_bounds__(NTHR, 2)
void lstm_ns(const int* __restrict__ cap, const int* __restrict__ cap_len,
             const float* __restrict__ embed,
             const float* __restrict__ bih, const float* __restrict__ bhh,
             const float* __restrict__ v_wn, const float* __restrict__ g_wn,
             const float* __restrict__ b_cls,
             const f16* __restrict__ Wc, float* __restrict__ out)
{
    __shared__ f16 A[2][ASTRIDE];   // 81.9KB: ping-pong [x|h] frag layout
    __shared__ int capS[NROW][TT];
    __shared__ float scaleS[2];

    const int tid = threadIdx.x;
    const int wg  = blockIdx.x;
    const int row0 = wg * NROW;
    const int wv = tid >> 6, ln = tid & 63, c = ln & 15, kg = ln >> 4;
    const int afrag = c * 32 + kg * 8;   // A-frag: row=lane&15, k-quad=lane>>4

    // ---- setup: tokens, head scale, zero BOTH A buffers ----
    for (int u = tid; u < NROW * TT; u += NTHR) {
        int rl = u / TT, t = u - rl * TT;
        capS[rl][t] = cap[(size_t)(row0 + rl) * TT + t];
    }
    if (tid < 2) {
        float s = 0.f;
        for (int k = 0; k < 300; ++k) { float v = v_wn[tid * 300 + k]; s += v * v; }
        scaleS[tid] = g_wn[tid] * rsqrtf(s);
    }
    {
        f16* Af = &A[0][0];
        for (int u = tid; u < 2 * ASTRIDE / 8; u += NTHR)
            *(f16x8*)&Af[u * 8] = (f16x8){0, 0, 0, 0, 0, 0, 0, 0};
    }
    __syncthreads();                // capS/zero visible BEFORE stage_x reads

    // ---- x staging into frag layout (chunks 0..36 full, 37 partial) ----
    auto stage_x = [&](int t, f16* An) {
        for (int u = tid; u < NROW * 38; u += NTHR) {
            int rl = u / 38, ch = u - rl * 38;
            const float* er = embed + (size_t)capS[rl][t] * 300;
            int k0 = ch * 8;
            size_t off = ((size_t)((rl >> 4) * NKT + (k0 >> 5))) * 512
                         + (rl & 15) * 32 + ((k0 >> 3) & 3) * 8;
            if (ch < 37) {
                float4 a = *(const float4*)(er + k0);
                float4 b = *(const float4*)(er + k0 + 4);
                f16x8 v;
                v[0] = (f16)a.x; v[1] = (f16)a.y; v[2] = (f16)a.z; v[3] = (f16)a.w;
                v[4] = (f16)b.x; v[5] = (f16)b.y; v[6] = (f16)b.z; v[7] = (f16)b.w;
                *(f16x8*)(An + off) = v;
            } else {                                 // k 296..299 only
                float4 a = *(const float4*)(er + 296);
                f16x4 v;
                v[0] = (f16)a.x; v[1] = (f16)a.y; v[2] = (f16)a.z; v[3] = (f16)a.w;
                *(f16x4*)(An + off) = v;
            }
        }
    };
    stage_x(0, A[0]);
    __syncthreads();

    // ---- per-wave tile assignment (jh-tiles 0..18 live; 19 = pad) ----
    int twl[3];
    twl[0] = wv; twl[1] = wv + 8; twl[2] = 16 + wv;
    bool live[3];
    live[0] = true; live[1] = true; live[2] = (wv < 3);

    int jh[3];
    float bias[3][4];
    int hadr[3];                                    // h write base (k=300+jh)
    #pragma unroll
    for (int tl = 0; tl < 3; ++tl) {
        int j = twl[tl] * 16 + c;
        jh[tl] = j;
        int hk = 300 + (j < 300 ? j : 299);
        hadr[tl] = (hk >> 5) * 512 + ((hk >> 3) & 3) * 8 + (hk & 7);
        #pragma unroll
        for (int g = 0; g < 4; ++g) {
            float bv = 0.f;
            if (live[tl] && j < 300) { int jj = g * 300 + j; bv = bih[jj] + bhh[jj]; }
            bias[tl][g] = bv;
        }
    }
    int lenr[2][4];
    #pragma unroll
    for (int m = 0; m < 2; ++m) {
        int rb = row0 + m * 16 + kg * 4;
        #pragma unroll
        for (int rg = 0; rg < 4; ++rg) lenr[m][rg] = cap_len[rb + rg];
    }

    float cst[2][3][4] = {};
    float hreg[2][3][4] = {};
    f32x4 acc[2][3][4];

    #pragma unroll 1
    for (int t = 0; t < STEPS; ++t) {
        const f16* Ab = A[t & 1];
        f16*       An = A[(t + 1) & 1];

        #pragma unroll
        for (int m = 0; m < 2; ++m)
            #pragma unroll
            for (int tl = 0; tl < 3; ++tl)
                #pragma unroll
                for (int g = 0; g < 4; ++g) {
                    float bv = bias[tl][g];
                    f32x4 b4 = {bv, bv, bv, bv};
                    acc[m][tl][g] = b4;
                }

        // K loop: A-frags from LDS (conflict-free), B-frags streamed from L2
        #pragma unroll 1
        for (int kt = 0; kt < NKT; ++kt) {
            f16x8 av0 = *(const f16x8*)&Ab[(0 * NKT + kt) * 512 + afrag];
            f16x8 av1 = *(const f16x8*)&Ab[(1 * NKT + kt) * 512 + afrag];
            #pragma unroll
            for (int tl = 0; tl < 3; ++tl) {
                if (!live[tl]) continue;             // wave-uniform
                #pragma unroll
                for (int g = 0; g < 4; ++g) {
                    f16x8 bv = *(const f16x8*)&Wc[
                        ((size_t)((g * 20 + twl[tl]) * NKT + kt)) * 512 + ln * 8];
                    acc[0][tl][g] = __builtin_amdgcn_mfma_f32_16x16x32_f16(av0, bv, acc[0][tl][g], 0, 0, 0);
                    acc[1][tl][g] = __builtin_amdgcn_mfma_f32_16x16x32_f16(av1, bv, acc[1][tl][g], 0, 0, 0);
                }
            }
        }

        // gates (i/f/g/o same-lane acc regs) + h(t+1) into An's h region
        #pragma unroll
        for (int m = 0; m < 2; ++m)
            #pragma unroll
            for (int tl = 0; tl < 3; ++tl) {
                if (!live[tl] || jh[tl] >= 300) continue;
                #pragma unroll
                for (int rg = 0; rg < 4; ++rg) {
                    bool upd = (t < lenr[m][rg]);
                    float iv = sigm(acc[m][tl][0][rg]);
                    float fv = sigm(acc[m][tl][1][rg]);
                    float gv = tanh_f(acc[m][tl][2][rg]);
                    float ov = sigm(acc[m][tl][3][rg]);
                    float cn = fv * cst[m][tl][rg] + iv * gv;
                    cn = upd ? cn : cst[m][tl][rg];
                    cst[m][tl][rg] = cn;
                    float hn = ov * tanh_f(cn);
                    hreg[m][tl][rg] = upd ? hn : hreg[m][tl][rg];
                    An[(size_t)(m * NKT) * 512 + hadr[tl]
                       + (size_t)(kg * 4 + rg) * 32] = (f16)hreg[m][tl][rg];
                }
            }

        if (t + 1 < STEPS) stage_x(t + 1, An);
        __syncthreads();    // intra-CU only: h/x visible, Ab free for rewrite
    }

    // ---- head: h(22) lives in A[STEPS&1] = A[0] ----
    const f16* hb = A[STEPS & 1];
    for (int u = tid; u < NROW * 2; u += NTHR) {
        int rl = u >> 1, cls = u & 1;
        float sc = scaleS[cls];
        const float* vr = v_wn + cls * 300;
        float s = 0.f;
        #pragma unroll 4
        for (int k = 0; k < 300; ++k) {
            int hk = 300 + k;
            size_t off = ((size_t)((rl >> 4) * NKT + (hk >> 5))) * 512
                         + (rl & 15) * 32 + ((hk >> 3) & 3) * 8 + (hk & 7);
            s += vr[k] * (float)hb[off];
        }
        out[(size_t)(row0 + rl) * 2 + cls] = sc * s + b_cls[cls];
    }
}

extern "C" void kernel_launch(void* const* d_in, const int* in_sizes, int n_in,
                              void* d_out, int out_size, void* d_ws, size_t ws_size,
                              hipStream_t stream) {
    const int*   cap     = (const int*)  d_in[0];
    const int*   cap_len = (const int*)  d_in[1];
    const float* embed   = (const float*)d_in[2];
    const float* W_ih    = (const float*)d_in[3];
    const float* W_hh    = (const float*)d_in[4];
    const float* b_ih    = (const float*)d_in[5];
    const float* b_hh    = (const float*)d_in[6];
    const float* v_wn    = (const float*)d_in[7];
    const float* g_wn    = (const float*)d_in[8];
    const float* b_cls   = (const float*)d_in[9];
    float* out = (float*)d_out;

    f16* Wc = (f16*)d_ws;            // 1520 frags x 1KB = 1.52 MB

    prep_w<<<1520, 64, 0, stream>>>(W_ih, W_hh, Wc);
    lstm_ns<<<NWGD, NTHR, 0, stream>>>(cap, cap_len, embed, b_ih, b_hh,
                                       v_wn, g_wn, b_cls, Wc, out);
}